// Round 3
// baseline (15.976 us; speedup 1.0000x reference)
//
#include <hip/hip_runtime.h>
#include <math.h>

#define HH 128      // image size
#define SS 32       // tile size
#define DD 8        // dilation
#define NSH 17      // 2*DD+1 shifts per axis
#define NPOS 289    // 17*17
#define NA 11       // angles -5..5
#define REG 48      // fm2 region size
#define BST 52      // Bsm LDS stride (floats), float4-aligned
#define BPAD 56     // leading pad (floats): row/col -1 bilinear taps stay in-bounds
#define BODD 53     // odd-stride B copy: conflict-free b32 row reads
#define AST 36      // As  LDS stride (floats)
#define NT  1024    // 16 waves
#define NBLK 256    // one block per (batch, tile)
#define PUBMASK 0x5A5A5A5Au  // publication color: poison^MASK is never a
                             // plausible small-positive-float bit pattern

__device__ __forceinline__ int iclip(int v, int lo, int hi) {
    return v < lo ? lo : (v > hi ? hi : v);
}

// ---- DPP wave reductions (VALU pipe, not LDS like __shfl/ds_bpermute) ----
// ctrl/rmask must be compile-time constants -> template parameters.
// Sum step: bound_ctrl=true, old=0 -> invalid/masked lanes contribute 0.
template <int CTRL, int RMASK>
__device__ __forceinline__ float dpp0(float x) {
    return __int_as_float(__builtin_amdgcn_update_dpp(
        0, __float_as_int(x), CTRL, RMASK, 0xf, true));
}
// Min step: old=x, bound_ctrl=false -> invalid/masked lanes yield x (no-op).
template <int CTRL, int RMASK>
__device__ __forceinline__ float dpps(float x) {
    return __int_as_float(__builtin_amdgcn_update_dpp(
        __float_as_int(x), __float_as_int(x), CTRL, RMASK, 0xf, false));
}
__device__ __forceinline__ float wsum64(float x) {   // total in lane 63
    x += dpp0<0x111, 0xf>(x);   // row_shr:1
    x += dpp0<0x112, 0xf>(x);   // row_shr:2
    x += dpp0<0x114, 0xf>(x);   // row_shr:4
    x += dpp0<0x118, 0xf>(x);   // row_shr:8
    x += dpp0<0x142, 0xa>(x);   // row_bcast:15 -> rows 1,3
    x += dpp0<0x143, 0xc>(x);   // row_bcast:31 -> rows 2,3
    return x;
}
__device__ __forceinline__ float wmin64(float x) {   // min in lane 63
    x = fminf(x, dpps<0x111, 0xf>(x));
    x = fminf(x, dpps<0x112, 0xf>(x));
    x = fminf(x, dpps<0x114, 0xf>(x));
    x = fminf(x, dpps<0x118, 0xf>(x));
    x = fminf(x, dpps<0x142, 0xa>(x));
    x = fminf(x, dpps<0x143, 0xc>(x));
    return x;
}
__device__ __forceinline__ float xor1_sum(float x) { // quad_perm [1,0,3,2]
    return x + __int_as_float(__builtin_amdgcn_update_dpp(
        0, __float_as_int(x), 0xB1, 0xf, 0xf, true));
}

__global__ __launch_bounds__(NT, 1) void tile_loss_kernel(
    const float* __restrict__ fm1, const float* __restrict__ fm2,
    unsigned* __restrict__ ws, float* __restrict__ out)
{
    // f32-rounded values of the f64 cos/sin(deg) the reference grids use
    const float CS[NA] = {
        0.99619469809174553f, 0.99756405025982420f, 0.99862953475457383f,
        0.99939082701909576f, 0.99984769515639127f, 1.0f,
        0.99984769515639127f, 0.99939082701909576f, 0.99862953475457383f,
        0.99756405025982420f, 0.99619469809174553f };
    const float SN[NA] = {
        -0.08715574274765817f, -0.06975647374412530f, -0.05233595624294383f,
        -0.03489949670250097f, -0.01745240643728351f, 0.0f,
         0.01745240643728351f,  0.03489949670250097f,  0.05233595624294383f,
         0.06975647374412530f,  0.08715574274765817f };

    int bid = blockIdx.x;          // 256 blocks: (b, tile)
    int b = bid >> 4, tile = bid & 15;
    int ty = tile >> 2, tx = tile & 3;
    int t = threadIdx.x;
    int wid = t >> 6, lane = t & 63;

    __shared__ float As[SS * AST];                        // fm1 tile
    __shared__ __align__(16) float Bsm[BPAD + REG * BST]; // fm2 region (padded front)
    __shared__ float Bodd[REG * BODD];      // odd-stride copy for corr b32 reads
    __shared__ float corrpart[SS * NPOS];   // [y][dy*17+dx]; reused as sv[] at end
    __shared__ float colsq[NSH * REG];      // [dy][xx]
    __shared__ float red[16];
    __shared__ float sa2_red[4];
    __shared__ float rnum[16][NA], rden[16][NA];
    __shared__ float qv[NA];
    __shared__ float sa2_sh;

    float* Bs = Bsm + BPAD;                 // logical region base

    const float* f1 = fm1 + b * HH * HH;
    const float* f2 = fm2 + b * HH * HH;

    int r_lo = iclip(ty * SS - DD, 0, HH - SS);
    int c_lo = iclip(tx * SS - DD, 0, HH - SS);

    // ---- stage fm1 tile (t<256) + sum of a^2; fm2 region (256<=t<832) ----
    if (t < 256) {
        int y = t >> 3, xq = (t & 7) << 2;
        float4 v = *reinterpret_cast<const float4*>(
            &f1[(ty * SS + y) * HH + tx * SS + xq]);
        *reinterpret_cast<float4*>(&As[y * AST + xq]) = v;
        float s = wsum64(v.x * v.x + v.y * v.y + v.z * v.z + v.w * v.w);
        if (lane == 63) sa2_red[wid] = s;
    } else if (t < 256 + REG * 12) {
        // Region can exceed the image for edge tiles: zero-fill OOB (garbage
        // never consumed by clipped (oy,ox), but the LOAD must stay in bounds).
        int i = t - 256;
        int ry = i / 12, xq = (i - ry * 12) << 2;
        int gy = r_lo + ry, gx = c_lo + xq;
        float4 v = make_float4(0.f, 0.f, 0.f, 0.f);
        if (gy < HH && gx + 3 < HH)   // gx mult of 4 -> fully in or fully out
            v = *reinterpret_cast<const float4*>(&f2[gy * HH + gx]);
        *reinterpret_cast<float4*>(&Bs[ry * BST + xq]) = v;
        float* bo = &Bodd[ry * BODD + xq];
        bo[0] = v.x; bo[1] = v.y; bo[2] = v.z; bo[3] = v.w;
    }
    __syncthreads();

    if (t == 0)
        sa2_sh = sa2_red[0] + sa2_red[1] + sa2_red[2] + sa2_red[3];

    if (t < SS * NSH) {
        // ======== corr: waves 0-8, one (y,dy) task, 2 x-chunks of 16 ========
        int y  = t / NSH;
        int dy = t - y * NSH;
        const float* BroO = &Bodd[(y + dy) * BODD];  // conflict-free b32 row
        const float* Arow = &As[y * AST];
        float acc[NSH];
        #pragma unroll
        for (int dx = 0; dx < NSH; ++dx) acc[dx] = 0.f;
        #pragma unroll
        for (int c = 0; c < 2; ++c) {
            float ar[16];
            #pragma unroll
            for (int q = 0; q < 4; ++q) {
                float4 v = *reinterpret_cast<const float4*>(
                    &Arow[(c << 4) + (q << 2)]);
                ar[4*q] = v.x; ar[4*q+1] = v.y;
                ar[4*q+2] = v.z; ar[4*q+3] = v.w;
            }
            float br[33];
            #pragma unroll
            for (int j = 0; j < 33; ++j) br[j] = BroO[(c << 4) + j];
            #pragma unroll
            for (int x = 0; x < 16; ++x) {
                #pragma unroll
                for (int dx = 0; dx < NSH; ++dx)
                    acc[dx] += ar[x] * br[x + dx];
            }
        }
        float* cp = &corrpart[y * NPOS + dy * NSH];
        #pragma unroll
        for (int dx = 0; dx < NSH; ++dx) cp[dx] = acc[dx];
    } else if (t < SS * NSH + 32) {
        // ======== rolling column sums of b^2: 32 threads, 48 cols ========
        int xx0 = t - SS * NSH;
        #pragma unroll
        for (int rep = 0; rep < 2; ++rep) {
            int xx = xx0 + (rep << 5);
            if (xx < REG) {
                float s = 0.f;
                #pragma unroll
                for (int y = 0; y < SS; ++y) {
                    float v = Bs[y * BST + xx];
                    s += v * v;
                }
                colsq[xx] = s;
                #pragma unroll
                for (int dy = 1; dy < NSH; ++dy) {
                    float vo = Bs[(dy - 1) * BST + xx];
                    float vn = Bs[(dy + SS - 1) * BST + xx];
                    s += vn * vn - vo * vo;
                    colsq[dy * REG + xx] = s;
                }
            }
        }
    } else {
        // ======== rotation: waves 9-15 (448 thr), 1024 px, 2-3 each ========
        int toy = ty * SS - r_lo;
        int tox = tx * SS - c_lo;
        int i = t - 576;
        // per-thread constant base for the bilinear taps
        const float* Bbase = &Bs[toy * BST + tox];

        float num_loc[NA], den_loc[NA];
        #pragma unroll
        for (int a = 0; a < NA; ++a) { num_loc[a] = 0.f; den_loc[a] = 0.f; }

        #pragma unroll
        for (int k = 0; k < 3; ++k) {
            int p = i + k * 448;
            if (p < SS * SS) {
                int y = p >> 5, x = p & 31;
                float a1 = As[y * AST + x];
                float xc = (float)x - 16.0f;
                float yc = (float)y - 16.0f;
                #pragma unroll
                for (int a = 0; a < NA; ++a) {
                    float al = CS[a], be = SN[a];
                    float sx = al * xc - be * yc + 16.0f;
                    float sy = be * xc + al * yc + 16.0f;
                    float x0f = floorf(sx), y0f = floorf(sy);
                    int x0 = (int)x0f, y0 = (int)y0f;
                    float fx = sx - x0f, fy = sy - y0f;
                    // window tests as single unsigned compares (same values)
                    float wx0 = ((unsigned)x0       < 32u) ? (1.f - fx) : 0.f;
                    float wx1 = ((unsigned)(x0 + 1) < 32u) ? fx         : 0.f;
                    float wy0 = ((unsigned)y0       < 32u) ? (1.f - fy) : 0.f;
                    float wy1 = ((unsigned)(y0 + 1) < 32u) ? fy         : 0.f;
                    // extended clamp to -1: one address, immediate-offset taps.
                    // Any tap consumed with nonzero weight reads the exact
                    // element the old per-tap clamp read; others are padded
                    // in-bounds garbage times zero weight.
                    int xi0 = iclip(x0, -1, SS - 1);
                    int yi0 = iclip(y0, -1, SS - 1);
                    const float* rp = &Bbase[yi0 * BST + xi0];
                    float b00 = rp[0],   b01 = rp[1];
                    float b10 = rp[BST], b11 = rp[BST + 1];
                    float rv = wy0 * (wx0 * b00 + wx1 * b01)
                             + wy1 * (wx0 * b10 + wx1 * b11);
                    float mv = (wx0 + wx1) * (wy0 + wy1);
                    float dd = a1 - rv;
                    num_loc[a] += dd * dd * mv;
                    den_loc[a] += mv;
                }
            }
        }

        #pragma unroll
        for (int a = 0; a < NA; ++a) {
            float nv = wsum64(num_loc[a]);
            float dv = wsum64(den_loc[a]);
            if (lane == 63) { rnum[wid][a] = nv; rden[wid][a] = dv; }
        }
    }
    __syncthreads();   // corrpart, colsq, rnum/rden ready

    // ======== per-angle combine (t<11) + SSD assembly (578 thr) ========
    if (t < NA) {
        float nv = 0.f, dv = 0.f;
        #pragma unroll
        for (int w = 9; w < 16; ++w) { nv += rnum[w][t]; dv += rden[w][t]; }
        qv[t] = nv / dv;
    }
    {
        float ssd_min = INFINITY;
        if (t < 2 * NPOS) {
            int pos = t >> 1, half = t & 1;
            int iy = pos / NSH, ix = pos - iy * NSH;
            int rs = iclip(ty * SS + iy - DD, 0, HH - SS);
            int cs = iclip(tx * SS + ix - DD, 0, HH - SS);
            int oy = rs - r_lo, ox = cs - c_lo;
            int j0 = half << 4;
            float c = 0.f, q = 0.f;
            #pragma unroll
            for (int j = 0; j < 16; ++j) {
                c += corrpart[(j0 + j) * NPOS + oy * NSH + ox];
                q += colsq[oy * REG + ox + j0 + j];
            }
            float part = xor1_sum(q - 2.f * c);
            ssd_min = (half == 0) ? (sa2_sh + part) : INFINITY;
        }
        ssd_min = wmin64(ssd_min);
        if (lane == 63) red[wid] = ssd_min;
    }
    __syncthreads();

    // ======== publish this block's tile loss (poison-safe protocol) ========
    // ws layout: V[256] = loss bits (relaxed), C[256] = bits^PUBMASK (release).
    // Consumer accepts iff C == V^PUBMASK and consumes V. Under any uniform
    // fill poison p: stale C needs p == p^PUBMASK (impossible); fresh C
    // implies fresh V by release->acquire ordering. So a consumed V is
    // always this run's true value.
    if (t == 0) {
        float s_min = INFINITY;
        #pragma unroll
        for (int w = 0; w < 16; ++w) s_min = fminf(s_min, red[w]);
        s_min *= (1.0f / 1024.0f);
        float r_min = qv[0];
        #pragma unroll
        for (int a = 1; a < NA; ++a) r_min = fminf(r_min, qv[a]);
        float loss = fminf(s_min, r_min);
        unsigned bits = __float_as_uint(loss);
        __hip_atomic_store(&ws[bid], bits,
                           __ATOMIC_RELAXED, __HIP_MEMORY_SCOPE_AGENT);
        __hip_atomic_store(&ws[256 + bid], bits ^ PUBMASK,
                           __ATOMIC_RELEASE, __HIP_MEMORY_SCOPE_AGENT);
    }

    // ======== block 0: gather 256 losses, per-batch top-8 sum ========
    if (bid == 0) {
        float* sv = corrpart;               // LDS reuse (corrpart is dead)
        if (t < 256) {
            unsigned c, v;
            for (;;) {
                c = __hip_atomic_load(&ws[256 + t],
                                      __ATOMIC_ACQUIRE, __HIP_MEMORY_SCOPE_AGENT);
                v = __hip_atomic_load(&ws[t],
                                      __ATOMIC_RELAXED, __HIP_MEMORY_SCOPE_AGENT);
                if (c == (v ^ PUBMASK)) break;
                __builtin_amdgcn_s_sleep(2);
            }
            sv[t] = __uint_as_float(v);
        }
        __syncthreads();
        if (t < 256) {
            int bb = t >> 4, i = t & 15;
            float v = sv[t];
            int rank = 0;
            #pragma unroll
            for (int j = 0; j < 16; ++j) {
                float u = sv[(bb << 4) | j];
                rank += (u < v || (u == v && j < i)) ? 1 : 0;
            }
            float sel = (rank < 8) ? v : 0.0f;
            sel += __shfl_down(sel, 8, 16);
            sel += __shfl_down(sel, 4, 16);
            sel += __shfl_down(sel, 2, 16);
            sel += __shfl_down(sel, 1, 16);
            if (i == 0) out[bb] = sel;
        }
    }
}

extern "C" void kernel_launch(void* const* d_in, const int* in_sizes, int n_in,
                              void* d_out, int out_size, void* d_ws, size_t ws_size,
                              hipStream_t stream) {
    const float* fm1 = (const float*)d_in[0];
    const float* fm2 = (const float*)d_in[1];
    float* out = (float*)d_out;
    unsigned* ws = (unsigned*)d_ws;   // V[256] + C[256]

    hipLaunchKernelGGL(tile_loss_kernel, dim3(NBLK), dim3(NT), 0, stream,
                       fm1, fm2, ws, out);
}

// Round 4
// 15.229 us; speedup vs baseline: 1.0491x; 1.0491x over previous
//
#include <hip/hip_runtime.h>
#include <math.h>

#define HH 128      // image size
#define SS 32       // tile size
#define DD 8        // dilation
#define NSH 17      // 2*DD+1 shifts per axis
#define NPOS 289    // 17*17
#define NA 11       // angles -5..5
#define REG 48      // fm2 region size
#define BST 52      // Bsm LDS stride (floats), float4-aligned
#define BPAD 56     // leading pad (floats): row/col -1 bilinear taps stay in-bounds
#define BODD 53     // odd-stride B copy: conflict-free b32 row reads
#define AST 36      // As  LDS stride (floats)
#define NT  1024    // 16 waves
#define NBLK 256    // one block per (batch, tile)

// NOTE (rounds 1/3): do NOT fuse the top-k via grid.sync (+35us) or via
// device-scope publish/spin handoff (+0.7us) — on MI355X cross-XCD
// synchronization costs more than a second graph-node dispatch.

__device__ __forceinline__ int iclip(int v, int lo, int hi) {
    return v < lo ? lo : (v > hi ? hi : v);
}

// ---- DPP wave reductions (VALU pipe, not LDS like __shfl/ds_bpermute) ----
// ctrl/rmask must be compile-time constants -> template parameters.
// Sum step: bound_ctrl=true, old=0 -> invalid/masked lanes contribute 0.
template <int CTRL, int RMASK>
__device__ __forceinline__ float dpp0(float x) {
    return __int_as_float(__builtin_amdgcn_update_dpp(
        0, __float_as_int(x), CTRL, RMASK, 0xf, true));
}
// Min step: old=x, bound_ctrl=false -> invalid/masked lanes yield x (no-op).
template <int CTRL, int RMASK>
__device__ __forceinline__ float dpps(float x) {
    return __int_as_float(__builtin_amdgcn_update_dpp(
        __float_as_int(x), __float_as_int(x), CTRL, RMASK, 0xf, false));
}
__device__ __forceinline__ float wsum64(float x) {   // total in lane 63
    x += dpp0<0x111, 0xf>(x);   // row_shr:1
    x += dpp0<0x112, 0xf>(x);   // row_shr:2
    x += dpp0<0x114, 0xf>(x);   // row_shr:4
    x += dpp0<0x118, 0xf>(x);   // row_shr:8
    x += dpp0<0x142, 0xa>(x);   // row_bcast:15 -> rows 1,3
    x += dpp0<0x143, 0xc>(x);   // row_bcast:31 -> rows 2,3
    return x;
}
__device__ __forceinline__ float wmin64(float x) {   // min in lane 63
    x = fminf(x, dpps<0x111, 0xf>(x));
    x = fminf(x, dpps<0x112, 0xf>(x));
    x = fminf(x, dpps<0x114, 0xf>(x));
    x = fminf(x, dpps<0x118, 0xf>(x));
    x = fminf(x, dpps<0x142, 0xa>(x));
    x = fminf(x, dpps<0x143, 0xc>(x));
    return x;
}
__device__ __forceinline__ float xor1_sum(float x) { // quad_perm [1,0,3,2]
    return x + __int_as_float(__builtin_amdgcn_update_dpp(
        0, __float_as_int(x), 0xB1, 0xf, 0xf, true));
}

__global__ __launch_bounds__(NT, 1) void tile_loss_kernel(
    const float* __restrict__ fm1, const float* __restrict__ fm2,
    float* __restrict__ tloss)
{
    // f32-rounded values of the f64 cos/sin(deg) the reference grids use
    const float CS[NA] = {
        0.99619469809174553f, 0.99756405025982420f, 0.99862953475457383f,
        0.99939082701909576f, 0.99984769515639127f, 1.0f,
        0.99984769515639127f, 0.99939082701909576f, 0.99862953475457383f,
        0.99756405025982420f, 0.99619469809174553f };
    const float SN[NA] = {
        -0.08715574274765817f, -0.06975647374412530f, -0.05233595624294383f,
        -0.03489949670250097f, -0.01745240643728351f, 0.0f,
         0.01745240643728351f,  0.03489949670250097f,  0.05233595624294383f,
         0.06975647374412530f,  0.08715574274765817f };

    int bid = blockIdx.x;          // 256 blocks: (b, tile)
    int b = bid >> 4, tile = bid & 15;
    int ty = tile >> 2, tx = tile & 3;
    int t = threadIdx.x;
    int wid = t >> 6, lane = t & 63;

    __shared__ float As[SS * AST];                        // fm1 tile
    __shared__ __align__(16) float Bsm[BPAD + REG * BST]; // fm2 region (padded front)
    __shared__ float Bodd[REG * BODD];      // odd-stride copy for corr b32 reads
    __shared__ float corrpart[SS * NPOS];   // [y][dy*17+dx]
    __shared__ float colsq[NSH * REG];      // [dy][xx]
    __shared__ float red[16];
    __shared__ float sa2_red[4];
    __shared__ float rnum[16][NA], rden[16][NA];
    __shared__ float qv[NA];
    __shared__ float sa2_sh;

    float* Bs = Bsm + BPAD;                 // logical region base

    const float* f1 = fm1 + b * HH * HH;
    const float* f2 = fm2 + b * HH * HH;

    int r_lo = iclip(ty * SS - DD, 0, HH - SS);
    int c_lo = iclip(tx * SS - DD, 0, HH - SS);

    // ---- stage fm1 tile (t<256) + sum of a^2; fm2 region (256<=t<832) ----
    if (t < 256) {
        int y = t >> 3, xq = (t & 7) << 2;
        float4 v = *reinterpret_cast<const float4*>(
            &f1[(ty * SS + y) * HH + tx * SS + xq]);
        *reinterpret_cast<float4*>(&As[y * AST + xq]) = v;
        float s = wsum64(v.x * v.x + v.y * v.y + v.z * v.z + v.w * v.w);
        if (lane == 63) sa2_red[wid] = s;
    } else if (t < 256 + REG * 12) {
        // Region can exceed the image for edge tiles: zero-fill OOB (garbage
        // never consumed by clipped (oy,ox), but the LOAD must stay in bounds).
        int i = t - 256;
        int ry = i / 12, xq = (i - ry * 12) << 2;
        int gy = r_lo + ry, gx = c_lo + xq;
        float4 v = make_float4(0.f, 0.f, 0.f, 0.f);
        if (gy < HH && gx + 3 < HH)   // gx mult of 4 -> fully in or fully out
            v = *reinterpret_cast<const float4*>(&f2[gy * HH + gx]);
        *reinterpret_cast<float4*>(&Bs[ry * BST + xq]) = v;
        float* bo = &Bodd[ry * BODD + xq];
        bo[0] = v.x; bo[1] = v.y; bo[2] = v.z; bo[3] = v.w;
    }
    __syncthreads();

    if (t == 0)
        sa2_sh = sa2_red[0] + sa2_red[1] + sa2_red[2] + sa2_red[3];

    if (t < SS * NSH) {
        // ======== corr: waves 0-8, one (y,dy) task, 2 x-chunks of 16 ========
        int y  = t / NSH;
        int dy = t - y * NSH;
        const float* BroO = &Bodd[(y + dy) * BODD];  // conflict-free b32 row
        const float* Arow = &As[y * AST];
        float acc[NSH];
        #pragma unroll
        for (int dx = 0; dx < NSH; ++dx) acc[dx] = 0.f;
        #pragma unroll
        for (int c = 0; c < 2; ++c) {
            float ar[16];
            #pragma unroll
            for (int q = 0; q < 4; ++q) {
                float4 v = *reinterpret_cast<const float4*>(
                    &Arow[(c << 4) + (q << 2)]);
                ar[4*q] = v.x; ar[4*q+1] = v.y;
                ar[4*q+2] = v.z; ar[4*q+3] = v.w;
            }
            float br[33];
            #pragma unroll
            for (int j = 0; j < 33; ++j) br[j] = BroO[(c << 4) + j];
            #pragma unroll
            for (int x = 0; x < 16; ++x) {
                #pragma unroll
                for (int dx = 0; dx < NSH; ++dx)
                    acc[dx] += ar[x] * br[x + dx];
            }
        }
        float* cp = &corrpart[y * NPOS + dy * NSH];
        #pragma unroll
        for (int dx = 0; dx < NSH; ++dx) cp[dx] = acc[dx];
    } else if (t < SS * NSH + 32) {
        // ======== rolling column sums of b^2: 32 threads, 48 cols ========
        int xx0 = t - SS * NSH;
        #pragma unroll
        for (int rep = 0; rep < 2; ++rep) {
            int xx = xx0 + (rep << 5);
            if (xx < REG) {
                float s = 0.f;
                #pragma unroll
                for (int y = 0; y < SS; ++y) {
                    float v = Bs[y * BST + xx];
                    s += v * v;
                }
                colsq[xx] = s;
                #pragma unroll
                for (int dy = 1; dy < NSH; ++dy) {
                    float vo = Bs[(dy - 1) * BST + xx];
                    float vn = Bs[(dy + SS - 1) * BST + xx];
                    s += vn * vn - vo * vo;
                    colsq[dy * REG + xx] = s;
                }
            }
        }
    } else {
        // ======== rotation: waves 9-15 (448 thr), 1024 px, 2-3 each ========
        int toy = ty * SS - r_lo;
        int tox = tx * SS - c_lo;
        int i = t - 576;
        // per-thread constant base for the bilinear taps
        const float* Bbase = &Bs[toy * BST + tox];

        float num_loc[NA], den_loc[NA];
        #pragma unroll
        for (int a = 0; a < NA; ++a) { num_loc[a] = 0.f; den_loc[a] = 0.f; }

        #pragma unroll
        for (int k = 0; k < 3; ++k) {
            int p = i + k * 448;
            if (p < SS * SS) {
                int y = p >> 5, x = p & 31;
                float a1 = As[y * AST + x];
                float xc = (float)x - 16.0f;
                float yc = (float)y - 16.0f;
                #pragma unroll
                for (int a = 0; a < NA; ++a) {
                    float al = CS[a], be = SN[a];
                    float sx = al * xc - be * yc + 16.0f;
                    float sy = be * xc + al * yc + 16.0f;
                    float x0f = floorf(sx), y0f = floorf(sy);
                    int x0 = (int)x0f, y0 = (int)y0f;
                    float fx = sx - x0f, fy = sy - y0f;
                    // window tests as single unsigned compares (same values)
                    float wx0 = ((unsigned)x0       < 32u) ? (1.f - fx) : 0.f;
                    float wx1 = ((unsigned)(x0 + 1) < 32u) ? fx         : 0.f;
                    float wy0 = ((unsigned)y0       < 32u) ? (1.f - fy) : 0.f;
                    float wy1 = ((unsigned)(y0 + 1) < 32u) ? fy         : 0.f;
                    // extended clamp to -1: one address, immediate-offset taps.
                    // Any tap consumed with nonzero weight reads the exact
                    // element the old per-tap clamp read; others are padded
                    // in-bounds garbage times zero weight.
                    int xi0 = iclip(x0, -1, SS - 1);
                    int yi0 = iclip(y0, -1, SS - 1);
                    const float* rp = &Bbase[yi0 * BST + xi0];
                    float b00 = rp[0],   b01 = rp[1];
                    float b10 = rp[BST], b11 = rp[BST + 1];
                    float rv = wy0 * (wx0 * b00 + wx1 * b01)
                             + wy1 * (wx0 * b10 + wx1 * b11);
                    float mv = (wx0 + wx1) * (wy0 + wy1);
                    float dd = a1 - rv;
                    num_loc[a] += dd * dd * mv;
                    den_loc[a] += mv;
                }
            }
        }

        #pragma unroll
        for (int a = 0; a < NA; ++a) {
            float nv = wsum64(num_loc[a]);
            float dv = wsum64(den_loc[a]);
            if (lane == 63) { rnum[wid][a] = nv; rden[wid][a] = dv; }
        }
    }
    __syncthreads();   // corrpart, colsq, rnum/rden ready

    // ======== per-angle combine (t<11) + SSD assembly (578 thr) ========
    if (t < NA) {
        float nv = 0.f, dv = 0.f;
        #pragma unroll
        for (int w = 9; w < 16; ++w) { nv += rnum[w][t]; dv += rden[w][t]; }
        qv[t] = nv / dv;
    }
    {
        float ssd_min = INFINITY;
        if (t < 2 * NPOS) {
            int pos = t >> 1, half = t & 1;
            int iy = pos / NSH, ix = pos - iy * NSH;
            int rs = iclip(ty * SS + iy - DD, 0, HH - SS);
            int cs = iclip(tx * SS + ix - DD, 0, HH - SS);
            int oy = rs - r_lo, ox = cs - c_lo;
            int j0 = half << 4;
            float c = 0.f, q = 0.f;
            #pragma unroll
            for (int j = 0; j < 16; ++j) {
                c += corrpart[(j0 + j) * NPOS + oy * NSH + ox];
                q += colsq[oy * REG + ox + j0 + j];
            }
            float part = xor1_sum(q - 2.f * c);
            ssd_min = (half == 0) ? (sa2_sh + part) : INFINITY;
        }
        ssd_min = wmin64(ssd_min);
        if (lane == 63) red[wid] = ssd_min;
    }
    __syncthreads();

    if (t == 0) {
        float s_min = INFINITY;
        #pragma unroll
        for (int w = 0; w < 16; ++w) s_min = fminf(s_min, red[w]);
        s_min *= (1.0f / 1024.0f);
        float r_min = qv[0];
        #pragma unroll
        for (int a = 1; a < NA; ++a) r_min = fminf(r_min, qv[a]);
        tloss[bid] = fminf(s_min, r_min);
    }
}

// Per batch: sum of the 8 smallest of its 16 tile losses.
__global__ __launch_bounds__(256) void topk_sum_kernel(
    const float* __restrict__ tloss, float* __restrict__ out)
{
    __shared__ float sv[256];
    int t = threadIdx.x;
    sv[t] = tloss[t];
    __syncthreads();
    int b = t >> 4, i = t & 15;
    float v = sv[t];
    int rank = 0;
    #pragma unroll
    for (int j = 0; j < 16; ++j) {
        float u = sv[(b << 4) | j];
        rank += (u < v || (u == v && j < i)) ? 1 : 0;
    }
    float sel = (rank < 8) ? v : 0.0f;
    sel += __shfl_down(sel, 8, 16);
    sel += __shfl_down(sel, 4, 16);
    sel += __shfl_down(sel, 2, 16);
    sel += __shfl_down(sel, 1, 16);
    if (i == 0) out[b] = sel;
}

extern "C" void kernel_launch(void* const* d_in, const int* in_sizes, int n_in,
                              void* d_out, int out_size, void* d_ws, size_t ws_size,
                              hipStream_t stream) {
    const float* fm1 = (const float*)d_in[0];
    const float* fm2 = (const float*)d_in[1];
    float* out = (float*)d_out;
    float* tloss = (float*)d_ws;   // 256 floats

    hipLaunchKernelGGL(tile_loss_kernel, dim3(NBLK), dim3(NT), 0, stream,
                       fm1, fm2, tloss);
    hipLaunchKernelGGL(topk_sum_kernel, dim3(1), dim3(256), 0, stream,
                       tloss, out);
}